// Round 16
// baseline (1738.134 us; speedup 1.0000x reference)
//
#include <hip/hip_runtime.h>
#include <stdint.h>

// B=4,H=16,S=2048,D=64 fp32 SDPA with materialized attn_prob.
// r16: DUAL q-block per block (32 rows, same k-range): QK^T(A),QK^T(B) ->
// ONE softmax barrier (per-wave (m,s); fac = 2^(m_w-M)/S) -> fused PV where
// each V chunk feeds both q-blocks (V traffic halved, 8 MFMA/chunk).
// Barriers per unit work: 6 -> 2. Spill-free at 2 blocks/CU.
#define SEQ 2048
#define DIM 64
#define QBLK 16
#define NWAVE 8
#define KPW 256
#define NCHUNK 8
#define THREADS 512
#define SCALE 0.125f
#define LOG2E 1.4426950408889634f
#define PSTR 40                 // plds row stride in bf16 (80 B)
#define VPAD 18                 // vbuf row stride in bf16 (36 B)
#define NTSTR (32*VPAD + 8)     // nt-subtile stride: 1168 B

typedef __attribute__((ext_vector_type(4))) float f32x4;
typedef __attribute__((ext_vector_type(4))) int   i32x4;
typedef __attribute__((ext_vector_type(8))) __bf16 bf16x8;

static __device__ __forceinline__ unsigned bfbits(float x) {
    union { __bf16 b; unsigned short u; } cv; cv.b = (__bf16)x; return (unsigned)cv.u;
}
static __device__ __forceinline__ float lo16(unsigned u) { return __uint_as_float(u << 16); }
static __device__ __forceinline__ float hi16(unsigned u) { return __uint_as_float(u & 0xffff0000u); }
static __device__ __forceinline__ bf16x8 cvt8(f32x4 a, f32x4 b) {
    bf16x8 f;
    f[0]=(__bf16)a[0]; f[1]=(__bf16)a[1]; f[2]=(__bf16)a[2]; f[3]=(__bf16)a[3];
    f[4]=(__bf16)b[0]; f[5]=(__bf16)b[1]; f[6]=(__bf16)b[2]; f[7]=(__bf16)b[3];
    return f;
}
static __device__ __forceinline__ unsigned nib4(i32x4 mm) {
    return (mm[0]?1u:0u) | (mm[1]?2u:0u) | (mm[2]?4u:0u) | (mm[3]?8u:0u);
}

struct WaveBuf {
    union {
        __bf16 vbuf[4 * NTSTR];      // V chunk, [nt][k][c] padded (4672 B)
        float  ctx[QBLK * DIM];      // ctx partial (4096 B, used after PV)
    };
};
struct SharedT {
    WaveBuf sw[NWAVE];                   // 37376 B
    __bf16 pldsA[NWAVE][QBLK][PSTR];     // 10240 B
    __bf16 pldsB[NWAVE][QBLK][PSTR];     // 10240 B
    float red_m[2][QBLK][NWAVE];         // 1024 B
    float red_s[2][QBLK][NWAVE];         // 1024 B
};                                       // 59904 B total

// One 8-tile QK^T half: full mask batch issued first (clean VMEM queue),
// staggered mq->bits conversion (first 4 at iter 3) to cap register peak.
#define QKT_HALF(MROWP, QFP, SCP, MBITSV, TB, LASTH)                           \
  {                                                                            \
    i32x4 mq0_ = *(const i32x4*)((MROWP) + 16*((TB)+0));                       \
    i32x4 mq1_ = *(const i32x4*)((MROWP) + 16*((TB)+1));                       \
    i32x4 mq2_ = *(const i32x4*)((MROWP) + 16*((TB)+2));                       \
    i32x4 mq3_ = *(const i32x4*)((MROWP) + 16*((TB)+3));                       \
    i32x4 mq4_ = *(const i32x4*)((MROWP) + 16*((TB)+4));                       \
    i32x4 mq5_ = *(const i32x4*)((MROWP) + 16*((TB)+5));                       \
    i32x4 mq6_ = *(const i32x4*)((MROWP) + 16*((TB)+6));                       \
    i32x4 mq7_ = *(const i32x4*)((MROWP) + 16*((TB)+7));                       \
    __builtin_amdgcn_sched_barrier(0);                                         \
    _Pragma("unroll")                                                          \
    for (int ct_ = 0; ct_ < 8; ++ct_) {                                        \
      if (ct_ == 3)                                                            \
        MBITSV |= nib4(mq0_) | (nib4(mq1_) << 4) | (nib4(mq2_) << 8)           \
                  | (nib4(mq3_) << 12);                                        \
      bf16x8 kf0_ = cvt8(kr[0], kr[1]);                                        \
      bf16x8 kf1_ = cvt8(kr[2], kr[3]);                                        \
      if (!(LASTH) || ct_ < 7) {                                               \
        const int nti_ = ((TB) + ct_ + 1) & 15;                                \
        const float* kn_ = Kb + (size_t)(wbase + nti_ * 16 + c) * DIM + 8 * g; \
        kr[0] = *(const f32x4*)(kn_);      kr[1] = *(const f32x4*)(kn_ + 4);   \
        kr[2] = *(const f32x4*)(kn_ + 32); kr[3] = *(const f32x4*)(kn_ + 36);  \
      }                                                                        \
      f32x4 acc_ = {0.f, 0.f, 0.f, 0.f};                                       \
      acc_ = __builtin_amdgcn_mfma_f32_16x16x32_bf16(kf0_, (QFP)[0], acc_, 0, 0, 0); \
      acc_ = __builtin_amdgcn_mfma_f32_16x16x32_bf16(kf1_, (QFP)[1], acc_, 0, 0, 0); \
      (SCP)[2*((TB)+ct_)]   = bfbits(acc_[0]*SCALE) | (bfbits(acc_[1]*SCALE) << 16); \
      (SCP)[2*((TB)+ct_)+1] = bfbits(acc_[2]*SCALE) | (bfbits(acc_[3]*SCALE) << 16); \
    }                                                                          \
    MBITSV |= (nib4(mq4_) << 16) | (nib4(mq5_) << 20) | (nib4(mq6_) << 24)     \
              | (nib4(mq7_) << 28);                                            \
  }

// Per-wave softmax sweep: apply mask, row max (wave-local), e = 2^(x-m), sum.
#define SMAX_SWEEP(SCP, MB0, MB1, MXV, SSV)                                    \
  float MXV = -3e38f;                                                          \
  _Pragma("unroll")                                                            \
  for (int ct_ = 0; ct_ < 16; ++ct_) {                                         \
    unsigned nib_ = ((ct_ < 8) ? ((MB0) >> (4*ct_)) : ((MB1) >> (4*(ct_-8)))) & 0xFu; \
    float x0_ = (nib_ & 1u) ? -1e9f : lo16((SCP)[2*ct_]);                      \
    float x1_ = (nib_ & 2u) ? -1e9f : hi16((SCP)[2*ct_]);                      \
    float x2_ = (nib_ & 4u) ? -1e9f : lo16((SCP)[2*ct_+1]);                    \
    float x3_ = (nib_ & 8u) ? -1e9f : hi16((SCP)[2*ct_+1]);                    \
    (SCP)[2*ct_]   = bfbits(x0_) | (bfbits(x1_) << 16);                        \
    (SCP)[2*ct_+1] = bfbits(x2_) | (bfbits(x3_) << 16);                        \
    MXV = fmaxf(MXV, fmaxf(fmaxf(x0_, x1_), fmaxf(x2_, x3_)));                 \
  }                                                                            \
  MXV = fmaxf(MXV, __shfl_xor(MXV, 16));                                       \
  MXV = fmaxf(MXV, __shfl_xor(MXV, 32));                                       \
  float SSV = 0.f;                                                             \
  _Pragma("unroll")                                                            \
  for (int i_ = 0; i_ < 32; ++i_) {                                            \
    float e0_ = exp2f((lo16((SCP)[i_]) - MXV) * LOG2E);                        \
    float e1_ = exp2f((hi16((SCP)[i_]) - MXV) * LOG2E);                        \
    SSV += e0_ + e1_;                                                          \
    (SCP)[i_] = bfbits(e0_) | (bfbits(e1_) << 16);                             \
  }                                                                            \
  SSV += __shfl_xor(SSV, 16);                                                  \
  SSV += __shfl_xor(SSV, 32);

__global__ __launch_bounds__(THREADS, 4)
void sdpa_mfma14(const float* __restrict__ Q, const float* __restrict__ K,
                 const float* __restrict__ V, const int* __restrict__ mask,
                 float* __restrict__ ctx_out, float* __restrict__ prob_out) {
    __shared__ SharedT su;

    // XCD-aware swizzle: 4096 blocks = 8 XCDs x 512 contiguous 32-row blocks.
    const int bid  = blockIdx.x;
    const int rb   = ((bid & 7) << 9) | (bid >> 3);
    const int bh   = rb >> 6;            // 64 super-blocks per (b,h)
    const int q0   = (rb & 63) * 32;
    const int t    = threadIdx.x;
    const int lane = t & 63;
    const int w    = t >> 6;
    const int g    = lane >> 4;          // 0..3
    const int c    = lane & 15;          // lane's q-row within sub-block

    const size_t bh_off = (size_t)bh * SEQ * DIM;
    const float* Qb = Q + bh_off;
    const float* Kb = K + bh_off;
    const float* Vb = V + bh_off;
    const int*   Mb = mask + (size_t)bh * SEQ * SEQ;
    const int wbase = w * KPW;

    const int* mrowA = Mb + (size_t)(q0 + c) * SEQ + wbase + 4 * g;
    const int* mrowB = Mb + (size_t)(q0 + 16 + c) * SEQ + wbase + 4 * g;

    // ---- Q^T A-fragments + K tile-0 preload (before any mask batch) ----
    bf16x8 qfA[2];
    {
        const float* qr = Qb + (size_t)(q0 + c) * DIM + 8 * g;
        qfA[0] = cvt8(*(const f32x4*)(qr),      *(const f32x4*)(qr + 4));
        qfA[1] = cvt8(*(const f32x4*)(qr + 32), *(const f32x4*)(qr + 36));
    }
    f32x4 kr[4];
    {
        const float* k0 = Kb + (size_t)(wbase + c) * DIM + 8 * g;
        kr[0] = *(const f32x4*)(k0);      kr[1] = *(const f32x4*)(k0 + 4);
        kr[2] = *(const f32x4*)(k0 + 32); kr[3] = *(const f32x4*)(k0 + 36);
    }

    unsigned sc_pkA[32], sc_pkB[32];
    unsigned mbA0 = 0u, mbA1 = 0u, mbB0 = 0u, mbB1 = 0u;

    // =============== QK^T(A) + sweep(A) ===============
    QKT_HALF(mrowA, qfA, sc_pkA, mbA0, 0, 0)
    QKT_HALF(mrowA, qfA, sc_pkA, mbA1, 8, 0)
    SMAX_SWEEP(sc_pkA, mbA0, mbA1, mxA, ssA)

    // =============== QK^T(B) + sweep(B) ===============
    bf16x8 qfB[2];
    {
        const float* qr = Qb + (size_t)(q0 + 16 + c) * DIM + 8 * g;
        qfB[0] = cvt8(*(const f32x4*)(qr),      *(const f32x4*)(qr + 4));
        qfB[1] = cvt8(*(const f32x4*)(qr + 32), *(const f32x4*)(qr + 36));
    }
    QKT_HALF(mrowB, qfB, sc_pkB, mbB0, 0, 0)
    QKT_HALF(mrowB, qfB, sc_pkB, mbB1, 8, 1)
    SMAX_SWEEP(sc_pkB, mbB0, mbB1, mxB, ssB)

    if (g == 0) {
        su.red_m[0][c][w] = mxA; su.red_s[0][c][w] = ssA;
        su.red_m[1][c][w] = mxB; su.red_s[1][c][w] = ssB;
    }

    // ---- V chunk-0 half-1 prefetch (in flight across the barrier) ----
    const int r_st = lane >> 4;
    const int cw   = (4 * c) & 15;
    const int ntw  = c >> 2;
    f32x4 vraw[4];
    {
        const float* vsrc = Vb + (size_t)(wbase + r_st) * DIM + 4 * c;
        #pragma unroll
        for (int i = 0; i < 4; ++i)
            vraw[i] = *(const f32x4*)(vsrc + (size_t)(4 * i) * DIM);
    }

    __syncthreads();   // THE softmax barrier (single)

    // global (M,S) per q-block; per-lane fac folds wave-local m adjustment
    float facA, facB;
    {
        float M = su.red_m[0][c][0];
        #pragma unroll
        for (int i = 1; i < NWAVE; ++i) M = fmaxf(M, su.red_m[0][c][i]);
        float S = 0.f;
        #pragma unroll
        for (int i = 0; i < NWAVE; ++i)
            S += su.red_s[0][c][i] * exp2f((su.red_m[0][c][i] - M) * LOG2E);
        facA = exp2f((mxA - M) * LOG2E) / S;
    }
    {
        float M = su.red_m[1][c][0];
        #pragma unroll
        for (int i = 1; i < NWAVE; ++i) M = fmaxf(M, su.red_m[1][c][i]);
        float S = 0.f;
        #pragma unroll
        for (int i = 0; i < NWAVE; ++i)
            S += su.red_s[1][c][i] * exp2f((su.red_m[1][c][i] - M) * LOG2E);
        facB = exp2f((mxB - M) * LOG2E) / S;
    }

    // =============== fused PV: one V chunk feeds BOTH q-blocks ===============
    f32x4 caccA[4], caccB[4];
    #pragma unroll
    for (int nt = 0; nt < 4; ++nt) {
        caccA[nt] = (f32x4){0.f, 0.f, 0.f, 0.f};
        caccB[nt] = (f32x4){0.f, 0.f, 0.f, 0.f};
    }
    float* prowA = prob_out + ((size_t)bh * SEQ + q0 + c) * SEQ + wbase;
    float* prowB = prowA + (size_t)16 * SEQ;
    __bf16* vbufW = su.sw[w].vbuf;

    #pragma unroll
    for (int cc = 0; cc < NCHUNK; ++cc) {
        // ---- A work (covers in-flight half-1 V loads) ----
        bf16x8 pfA;
        {
            unsigned a0 = sc_pkA[4*cc], a1 = sc_pkA[4*cc+1];
            unsigned a2 = sc_pkA[4*cc+2], a3 = sc_pkA[4*cc+3];
            f32x4 pn0 = { lo16(a0)*facA, hi16(a0)*facA, lo16(a1)*facA, hi16(a1)*facA };
            f32x4 pn1 = { lo16(a2)*facA, hi16(a2)*facA, lo16(a3)*facA, hi16(a3)*facA };
            *(f32x4*)(prowA + 32*cc + 4*g)      = pn0;
            *(f32x4*)(prowA + 32*cc + 16 + 4*g) = pn1;
            uint2 ua; ua.x = a0; ua.y = a1;
            uint2 ub; ub.x = a2; ub.y = a3;
            *(uint2*)&su.pldsA[w][c][4*g]      = ua;
            *(uint2*)&su.pldsA[w][c][16+4*g]   = ub;
            pfA = *(const bf16x8*)&su.pldsA[w][c][8*g];
        }
        // ---- stage half 1 (rows 0..15 of chunk) ----
        #pragma unroll
        for (int i = 0; i < 4; ++i) {
            ushort2 lo_, hi_;
            lo_.x = (unsigned short)bfbits(vraw[i][0]);
            lo_.y = (unsigned short)bfbits(vraw[i][1]);
            hi_.x = (unsigned short)bfbits(vraw[i][2]);
            hi_.y = (unsigned short)bfbits(vraw[i][3]);
            __bf16* p = &vbufW[ntw * NTSTR + (4*i + r_st) * VPAD + cw];
            *(ushort2*)p = lo_;
            *(ushort2*)(p + 2) = hi_;
        }
        // ---- issue half-2 loads ----
        {
            const float* vsrc = Vb + (size_t)(wbase + cc*32 + 16 + r_st) * DIM + 4*c;
            #pragma unroll
            for (int i = 0; i < 4; ++i)
                vraw[i] = *(const f32x4*)(vsrc + (size_t)(4 * i) * DIM);
        }
        // ---- B work (covers half-2 loads) ----
        bf16x8 pfB;
        {
            unsigned b0 = sc_pkB[4*cc], b1 = sc_pkB[4*cc+1];
            unsigned b2 = sc_pkB[4*cc+2], b3 = sc_pkB[4*cc+3];
            f32x4 pn0 = { lo16(b0)*facB, hi16(b0)*facB, lo16(b1)*facB, hi16(b1)*facB };
            f32x4 pn1 = { lo16(b2)*facB, hi16(b2)*facB, lo16(b3)*facB, hi16(b3)*facB };
            *(f32x4*)(prowB + 32*cc + 4*g)      = pn0;
            *(f32x4*)(prowB + 32*cc + 16 + 4*g) = pn1;
            uint2 ua; ua.x = b0; ua.y = b1;
            uint2 ub; ub.x = b2; ub.y = b3;
            *(uint2*)&su.pldsB[w][c][4*g]      = ua;
            *(uint2*)&su.pldsB[w][c][16+4*g]   = ub;
            pfB = *(const bf16x8*)&su.pldsB[w][c][8*g];
        }
        // ---- stage half 2 (rows 16..31) ----
        #pragma unroll
        for (int i = 0; i < 4; ++i) {
            ushort2 lo_, hi_;
            lo_.x = (unsigned short)bfbits(vraw[i][0]);
            lo_.y = (unsigned short)bfbits(vraw[i][1]);
            hi_.x = (unsigned short)bfbits(vraw[i][2]);
            hi_.y = (unsigned short)bfbits(vraw[i][3]);
            __bf16* p = &vbufW[ntw * NTSTR + (16 + 4*i + r_st) * VPAD + cw];
            *(ushort2*)p = lo_;
            *(ushort2*)(p + 2) = hi_;
        }
        // ---- issue next chunk's half-1 loads (covered by MFMA + next A work) ----
        if (cc + 1 < NCHUNK) {
            const float* vsrc = Vb + (size_t)(wbase + (cc+1)*32 + r_st) * DIM + 4*c;
            #pragma unroll
            for (int i = 0; i < 4; ++i)
                vraw[i] = *(const f32x4*)(vsrc + (size_t)(4 * i) * DIM);
        }
        // ---- V fragments (read once, feed both q-blocks) + 8 MFMA ----
        bf16x8 vfr[4];
        #pragma unroll
        for (int nt = 0; nt < 4; ++nt) {
            bf16x8 f;
            #pragma unroll
            for (int j = 0; j < 8; ++j)
                f[j] = vbufW[nt * NTSTR + (8*g + j) * VPAD + c];
            vfr[nt] = f;
        }
        __builtin_amdgcn_s_setprio(1);
        #pragma unroll
        for (int nt = 0; nt < 4; ++nt) {
            caccA[nt] = __builtin_amdgcn_mfma_f32_16x16x32_bf16(pfA, vfr[nt], caccA[nt], 0, 0, 0);
            caccB[nt] = __builtin_amdgcn_mfma_f32_16x16x32_bf16(pfB, vfr[nt], caccB[nt], 0, 0, 0);
        }
        __builtin_amdgcn_s_setprio(0);
    }

    // =============== epilogue: two sequential ctx reductions ===============
    float invrA[4], invrB[4];
    #pragma unroll
    for (int jr = 0; jr < 4; ++jr) {
        invrA[jr] = __shfl(facA, 4*g + jr);
        invrB[jr] = __shfl(facB, 4*g + jr);
    }
    #pragma unroll
    for (int nt = 0; nt < 4; ++nt)
        #pragma unroll
        for (int jr = 0; jr < 4; ++jr)
            su.sw[w].ctx[(4*g + jr) * DIM + nt*16 + c] = caccA[nt][jr] * invrA[jr];
    __syncthreads();
    {
        int e = t * 2;
        float2 a = make_float2(0.f, 0.f);
        #pragma unroll
        for (int i = 0; i < NWAVE; ++i) {
            float2 v = *(const float2*)&su.sw[i].ctx[e];
            a.x += v.x; a.y += v.y;
        }
        *(float2*)(ctx_out + ((size_t)bh * SEQ + q0) * DIM + e) = a;
    }
    __syncthreads();
    #pragma unroll
    for (int nt = 0; nt < 4; ++nt)
        #pragma unroll
        for (int jr = 0; jr < 4; ++jr)
            su.sw[w].ctx[(4*g + jr) * DIM + nt*16 + c] = caccB[nt][jr] * invrB[jr];
    __syncthreads();
    {
        int e = t * 2;
        float2 a = make_float2(0.f, 0.f);
        #pragma unroll
        for (int i = 0; i < NWAVE; ++i) {
            float2 v = *(const float2*)&su.sw[i].ctx[e];
            a.x += v.x; a.y += v.y;
        }
        *(float2*)(ctx_out + ((size_t)bh * SEQ + q0 + 16) * DIM + e) = a;
    }
}

extern "C" void kernel_launch(void* const* d_in, const int* in_sizes, int n_in,
                              void* d_out, int out_size, void* d_ws, size_t ws_size,
                              hipStream_t stream) {
    const float* Q = (const float*)d_in[0];
    const float* K = (const float*)d_in[1];
    const float* V = (const float*)d_in[2];
    const int* mask = (const int*)d_in[3];
    float* ctx  = (float*)d_out;
    float* prob = (float*)d_out + (size_t)4 * 16 * SEQ * DIM;

    dim3 grid(64 * (SEQ / 32));   // 4096 blocks (32 q-rows each), divisible by 8
    dim3 block(THREADS);
    sdpa_mfma14<<<grid, block, 0, stream>>>(Q, K, V, mask, ctx, prob);
}

// Round 17
// 1251.573 us; speedup vs baseline: 1.3888x; 1.3888x over previous
//
#include <hip/hip_runtime.h>
#include <stdint.h>

// B=4,H=16,S=2048,D=64 fp32 SDPA with materialized attn_prob.
// r17 = r15 base + software-pipelined QK^T with class-ordered rolling VMEM
// queues: K always 1 pair ahead (issued FIRST), mask 1.5-2 batches ahead
// (issued AFTER K), so K waits never drain mask loads, and the HBM mask
// stream stays continuously in flight through the whole QK^T phase.
#define SEQ 2048
#define DIM 64
#define QBLK 16
#define NWAVE 8
#define KPW 256
#define NCT 16
#define NCHUNK 8
#define THREADS 512
#define SCALE 0.125f
#define LOG2E 1.4426950408889634f
#define PSTR 40                 // plds row stride in bf16 (80 B)
#define VPAD 18                 // vbuf row stride in bf16 (36 B)
#define NTSTR (32*VPAD + 8)     // nt-subtile stride: 1168 B

typedef __attribute__((ext_vector_type(4))) float f32x4;
typedef __attribute__((ext_vector_type(4))) int   i32x4;
typedef __attribute__((ext_vector_type(8))) __bf16 bf16x8;

static __device__ __forceinline__ unsigned bfbits(float x) {
    union { __bf16 b; unsigned short u; } cv; cv.b = (__bf16)x; return (unsigned)cv.u;
}
static __device__ __forceinline__ float lo16(unsigned u) { return __uint_as_float(u << 16); }
static __device__ __forceinline__ float hi16(unsigned u) { return __uint_as_float(u & 0xffff0000u); }
static __device__ __forceinline__ bf16x8 cvt8(f32x4 a, f32x4 b) {
    bf16x8 f;
    f[0]=(__bf16)a[0]; f[1]=(__bf16)a[1]; f[2]=(__bf16)a[2]; f[3]=(__bf16)a[3];
    f[4]=(__bf16)b[0]; f[5]=(__bf16)b[1]; f[6]=(__bf16)b[2]; f[7]=(__bf16)b[3];
    return f;
}
static __device__ __forceinline__ unsigned nib4(i32x4 mm) {
    return (mm[0]?1u:0u) | (mm[1]?2u:0u) | (mm[2]?4u:0u) | (mm[3]?8u:0u);
}

struct WaveBuf {
    union {
        __bf16 vbuf[4 * NTSTR];      // V chunk, [nt][k][c] padded
        float  ctx[QBLK * DIM];      // ctx partial (used after PV)
    };
};
struct SharedT {
    WaveBuf sw[NWAVE];
    __bf16 plds[NWAVE][QBLK][PSTR];
    float red_m[QBLK][NWAVE];
    float red_s[QBLK][NWAVE];
};

__global__ __launch_bounds__(THREADS, 4)
void sdpa_mfma15(const float* __restrict__ Q, const float* __restrict__ K,
                 const float* __restrict__ V, const int* __restrict__ mask,
                 float* __restrict__ ctx_out, float* __restrict__ prob_out) {
    __shared__ SharedT su;

    // XCD-aware swizzle: 8192 = 8 XCDs x 1024 contiguous q-blocks (8 bh per XCD).
    const int rb   = ((blockIdx.x & 7) << 10) + (blockIdx.x >> 3);
    const int bh   = rb >> 7;
    const int q0   = (rb & 127) * QBLK;
    const int t    = threadIdx.x;
    const int lane = t & 63;
    const int w    = t >> 6;
    const int g    = lane >> 4;          // 0..3
    const int c    = lane & 15;          // lane's q-row (and N-col)

    const size_t bh_off = (size_t)bh * SEQ * DIM;
    const float* Qb = Q + bh_off;
    const float* Kb = K + bh_off;
    const float* Vb = V + bh_off;
    const int*   Mb = mask + (size_t)bh * SEQ * SEQ;
    const int wbase = w * KPW;

    // ---- Q^T B-fragments ----
    bf16x8 qf[2];
    {
        const float* qr = Qb + (size_t)(q0 + c) * DIM + 8 * g;
        qf[0] = cvt8(*(const f32x4*)(qr),      *(const f32x4*)(qr + 4));
        qf[1] = cvt8(*(const f32x4*)(qr + 32), *(const f32x4*)(qr + 36));
    }

    // =============== QK^T: 8 tile-pairs, rolling class-ordered queues ===============
    // queue discipline: K(p+1) issued FIRST each iteration; mask batches issued
    // AFTER K, consumed >=2 pairs later. K waits never drain the mask stream.
    unsigned sc_pk[2 * NCT];             // 64 scores, packed bf16, UNMASKED
    unsigned mbits0 = 0u, mbits1 = 0u;   // 64 mask bits (4 per tile)
    const int* mrow = Mb + (size_t)(q0 + c) * SEQ + wbase + 4 * g;

    i32x4 mqA[4], mqB[4];
    #pragma unroll
    for (int j = 0; j < 4; ++j) mqA[j] = *(const i32x4*)(mrow + 16 * j);         // tiles 0-3
    #pragma unroll
    for (int j = 0; j < 4; ++j) mqB[j] = *(const i32x4*)(mrow + 16 * (4 + j));   // tiles 4-7
    __builtin_amdgcn_sched_barrier(0);

    f32x4 knxt[8];                        // raw K for one pair (2 tiles x 4 f32x4)
    #pragma unroll
    for (int tt = 0; tt < 2; ++tt) {
        const float* kp = Kb + (size_t)(wbase + tt * 16 + c) * DIM + 8 * g;
        knxt[4*tt+0] = *(const f32x4*)(kp);
        knxt[4*tt+1] = *(const f32x4*)(kp + 4);
        knxt[4*tt+2] = *(const f32x4*)(kp + 32);
        knxt[4*tt+3] = *(const f32x4*)(kp + 36);
    }
    __builtin_amdgcn_sched_barrier(0);

    #pragma unroll
    for (int p = 0; p < 8; ++p) {
        // pair p's K arrived (counted vmcnt by compiler); cvt frees the raw regs
        bf16x8 kf[4];
        kf[0] = cvt8(knxt[0], knxt[1]);
        kf[1] = cvt8(knxt[2], knxt[3]);
        kf[2] = cvt8(knxt[4], knxt[5]);
        kf[3] = cvt8(knxt[6], knxt[7]);
        // issue pair p+1's K loads FIRST (head of queue)
        if (p + 1 < 8) {
            #pragma unroll
            for (int tt = 0; tt < 2; ++tt) {
                const float* kp = Kb + (size_t)(wbase + ((p + 1) * 2 + tt) * 16 + c) * DIM + 8 * g;
                knxt[4*tt+0] = *(const f32x4*)(kp);
                knxt[4*tt+1] = *(const f32x4*)(kp + 4);
                knxt[4*tt+2] = *(const f32x4*)(kp + 32);
                knxt[4*tt+3] = *(const f32x4*)(kp + 36);
            }
        }
        // mask housekeeping: convert arrived batch (score-independent), re-arm AFTER K
        if (p == 1) {
            mbits0 |= nib4(mqA[0]) | (nib4(mqA[1]) << 4) | (nib4(mqA[2]) << 8) | (nib4(mqA[3]) << 12);
            #pragma unroll
            for (int j = 0; j < 4; ++j) mqA[j] = *(const i32x4*)(mrow + 16 * (8 + j));   // tiles 8-11
        }
        if (p == 3) {
            mbits0 |= (nib4(mqB[0]) << 16) | (nib4(mqB[1]) << 20) | (nib4(mqB[2]) << 24) | (nib4(mqB[3]) << 28);
            #pragma unroll
            for (int j = 0; j < 4; ++j) mqB[j] = *(const i32x4*)(mrow + 16 * (12 + j));  // tiles 12-15
        }
        if (p == 5)
            mbits1 |= nib4(mqA[0]) | (nib4(mqA[1]) << 4) | (nib4(mqA[2]) << 8) | (nib4(mqA[3]) << 12);

        // 2 tiles of MFMA + pack
        #pragma unroll
        for (int tt = 0; tt < 2; ++tt) {
            f32x4 acc = {0.f, 0.f, 0.f, 0.f};
            acc = __builtin_amdgcn_mfma_f32_16x16x32_bf16(kf[2*tt],     qf[0], acc, 0, 0, 0);
            acc = __builtin_amdgcn_mfma_f32_16x16x32_bf16(kf[2*tt + 1], qf[1], acc, 0, 0, 0);
            const int ct = 2 * p + tt;
            sc_pk[2*ct]     = bfbits(acc[0] * SCALE) | (bfbits(acc[1] * SCALE) << 16);
            sc_pk[2*ct + 1] = bfbits(acc[2] * SCALE) | (bfbits(acc[3] * SCALE) << 16);
        }
    }
    mbits1 |= (nib4(mqB[0]) << 16) | (nib4(mqB[1]) << 20) | (nib4(mqB[2]) << 24) | (nib4(mqB[3]) << 28);

    // ---- V chunk-0 prefetch: in flight across mask sweep + softmax barriers ----
    const int r_st = lane >> 4;
    const int cw   = (4 * c) & 15;
    const int ntw  = c >> 2;
    f32x4 vrawA[4], vrawB[4];
    {
        const float* vsrc = Vb + (size_t)(wbase + r_st) * DIM + 4 * c;
        #pragma unroll
        for (int i = 0; i < 4; ++i) {
            vrawA[i] = *(const f32x4*)(vsrc + (size_t)(4 * i) * DIM);
            vrawB[i] = *(const f32x4*)(vsrc + (size_t)(16 + 4 * i) * DIM);
        }
    }

    // apply mask to packed scores (branchless select)
    #pragma unroll
    for (int ct = 0; ct < NCT; ++ct) {
        unsigned nib = ((ct < 8) ? (mbits0 >> (4 * ct)) : (mbits1 >> (4 * (ct - 8)))) & 0xFu;
        float x0 = (nib & 1u) ? -1e9f : lo16(sc_pk[2 * ct]);
        float x1 = (nib & 2u) ? -1e9f : hi16(sc_pk[2 * ct]);
        float x2 = (nib & 4u) ? -1e9f : lo16(sc_pk[2 * ct + 1]);
        float x3 = (nib & 8u) ? -1e9f : hi16(sc_pk[2 * ct + 1]);
        sc_pk[2 * ct]     = bfbits(x0) | (bfbits(x1) << 16);
        sc_pk[2 * ct + 1] = bfbits(x2) | (bfbits(x3) << 16);
    }

    // =============== softmax (lane owns row q=c) ===============
    float mx = -3e38f;
    #pragma unroll
    for (int i = 0; i < 2 * NCT; ++i)
        mx = fmaxf(mx, fmaxf(lo16(sc_pk[i]), hi16(sc_pk[i])));
    mx = fmaxf(mx, __shfl_xor(mx, 16));
    mx = fmaxf(mx, __shfl_xor(mx, 32));
    if (g == 0) su.red_m[c][w] = mx;
    __syncthreads();
    float M = su.red_m[c][0];
    #pragma unroll
    for (int i = 1; i < NWAVE; ++i) M = fmaxf(M, su.red_m[c][i]);

    float sum = 0.f;
    #pragma unroll
    for (int i = 0; i < 2 * NCT; ++i) {
        float e0 = exp2f((lo16(sc_pk[i]) - M) * LOG2E);
        float e1 = exp2f((hi16(sc_pk[i]) - M) * LOG2E);
        sum += e0 + e1;
        sc_pk[i] = bfbits(e0) | (bfbits(e1) << 16);   // raw e, bf16-packed
    }
    sum += __shfl_xor(sum, 16);
    sum += __shfl_xor(sum, 32);
    if (g == 0) su.red_s[c][w] = sum;
    __syncthreads();
    float S = 0.f;
    #pragma unroll
    for (int i = 0; i < NWAVE; ++i) S += su.red_s[c][i];
    const float inv = 1.0f / S;
    float invr[4];
    #pragma unroll
    for (int jr = 0; jr < 4; ++jr) invr[jr] = __shfl(inv, 4 * g + jr);

    // =============== PV + prob write, stage-then-reload V pipeline ===============
    f32x4 cacc[4];
    #pragma unroll
    for (int nt = 0; nt < 4; ++nt) cacc[nt] = (f32x4){0.f, 0.f, 0.f, 0.f};

    float* prow = prob_out + ((size_t)bh * SEQ + (q0 + c)) * SEQ + wbase;
    __bf16* vbufW = su.sw[w].vbuf;

    #pragma unroll
    for (int cc = 0; cc < NCHUNK; ++cc) {
        // stage chunk loaded last iteration / prologue
        #pragma unroll
        for (int i = 0; i < 4; ++i) {
            ushort2 lo_, hi_;
            lo_.x = (unsigned short)bfbits(vrawA[i][0]);
            lo_.y = (unsigned short)bfbits(vrawA[i][1]);
            hi_.x = (unsigned short)bfbits(vrawA[i][2]);
            hi_.y = (unsigned short)bfbits(vrawA[i][3]);
            __bf16* p = &vbufW[ntw * NTSTR + (4 * i + r_st) * VPAD + cw];
            *(ushort2*)p = lo_;
            *(ushort2*)(p + 2) = hi_;
        }
        #pragma unroll
        for (int i = 0; i < 4; ++i) {
            ushort2 lo_, hi_;
            lo_.x = (unsigned short)bfbits(vrawB[i][0]);
            lo_.y = (unsigned short)bfbits(vrawB[i][1]);
            hi_.x = (unsigned short)bfbits(vrawB[i][2]);
            hi_.y = (unsigned short)bfbits(vrawB[i][3]);
            __bf16* p = &vbufW[ntw * NTSTR + (16 + 4 * i + r_st) * VPAD + cw];
            *(ushort2*)p = lo_;
            *(ushort2*)(p + 2) = hi_;
        }
        // issue NEXT chunk's loads (only loads in this phase's queue)
        if (cc + 1 < NCHUNK) {
            const float* vsrc = Vb + (size_t)(wbase + (cc + 1) * 32 + r_st) * DIM + 4 * c;
            #pragma unroll
            for (int i = 0; i < 4; ++i) {
                vrawA[i] = *(const f32x4*)(vsrc + (size_t)(4 * i) * DIM);
                vrawB[i] = *(const f32x4*)(vsrc + (size_t)(16 + 4 * i) * DIM);
            }
        }

        // prob writes (normalized f32) + plds (raw bf16 e)
        unsigned pkA0 = sc_pk[4 * cc],     pkA1 = sc_pk[4 * cc + 1];
        unsigned pkB0 = sc_pk[4 * cc + 2], pkB1 = sc_pk[4 * cc + 3];
        {
            f32x4 pnA = { lo16(pkA0) * inv, hi16(pkA0) * inv, lo16(pkA1) * inv, hi16(pkA1) * inv };
            f32x4 pnB = { lo16(pkB0) * inv, hi16(pkB0) * inv, lo16(pkB1) * inv, hi16(pkB1) * inv };
            *(f32x4*)(prow + 32 * cc + 4 * g)      = pnA;
            *(f32x4*)(prow + 32 * cc + 16 + 4 * g) = pnB;
        }
        {
            uint2 ua; ua.x = pkA0; ua.y = pkA1;
            uint2 ub; ub.x = pkB0; ub.y = pkB1;
            *(uint2*)&su.plds[w][c][4 * g]      = ua;
            *(uint2*)&su.plds[w][c][16 + 4 * g] = ub;
        }
        bf16x8 pf = *(const bf16x8*)&su.plds[w][c][8 * g];

        // V B-frags: conflict-free scalar column reads
        bf16x8 vfr[4];
        #pragma unroll
        for (int nt = 0; nt < 4; ++nt) {
            bf16x8 f;
            #pragma unroll
            for (int j = 0; j < 8; ++j)
                f[j] = vbufW[nt * NTSTR + (8 * g + j) * VPAD + c];
            vfr[nt] = f;
        }

        __builtin_amdgcn_s_setprio(1);
        #pragma unroll
        for (int nt = 0; nt < 4; ++nt)
            cacc[nt] = __builtin_amdgcn_mfma_f32_16x16x32_bf16(pf, vfr[nt], cacc[nt], 0, 0, 0);
        __builtin_amdgcn_s_setprio(0);
    }

    // =============== ctx partials (scaled by per-row inv) + cross-wave reduce ===============
    #pragma unroll
    for (int nt = 0; nt < 4; ++nt)
        #pragma unroll
        for (int jr = 0; jr < 4; ++jr)
            su.sw[w].ctx[(4 * g + jr) * DIM + nt * 16 + c] = cacc[nt][jr] * invr[jr];
    __syncthreads();
    {
        int e = t * 2;
        float2 a = make_float2(0.f, 0.f);
        #pragma unroll
        for (int i = 0; i < NWAVE; ++i) {
            float2 v = *(const float2*)&su.sw[i].ctx[e];
            a.x += v.x; a.y += v.y;
        }
        *(float2*)(ctx_out + ((size_t)bh * SEQ + q0) * DIM + e) = a;
    }
}

extern "C" void kernel_launch(void* const* d_in, const int* in_sizes, int n_in,
                              void* d_out, int out_size, void* d_ws, size_t ws_size,
                              hipStream_t stream) {
    const float* Q = (const float*)d_in[0];
    const float* K = (const float*)d_in[1];
    const float* V = (const float*)d_in[2];
    const int* mask = (const int*)d_in[3];
    float* ctx  = (float*)d_out;
    float* prob = (float*)d_out + (size_t)4 * 16 * SEQ * DIM;

    dim3 grid(64 * (SEQ / QBLK));   // 8192, divisible by 8 XCDs
    dim3 block(THREADS);
    sdpa_mfma15<<<grid, block, 0, stream>>>(Q, K, V, mask, ctx, prob);
}

// Round 18
// 1000.802 us; speedup vs baseline: 1.7367x; 1.2506x over previous
//
#include <hip/hip_runtime.h>
#include <stdint.h>

// B=4,H=16,S=2048,D=64 fp32 SDPA with materialized attn_prob.
// r18 = r15 (best, 979us) + two state-neutral refinements:
//  (1) single-barrier softmax: per-wave (mx, s_w) -> one sync -> fac=2^(mx-M)/S
//  (2) P-fragment via shfl (r4 mapping, exonerated) -- no plds round-trip.
#define SEQ 2048
#define DIM 64
#define QBLK 16
#define NWAVE 8
#define KPW 256
#define NCT 16
#define NCHUNK 8
#define THREADS 512
#define SCALE 0.125f
#define LOG2E 1.4426950408889634f
#define VPAD 18                 // vbuf row stride in bf16 (36 B)
#define NTSTR (32*VPAD + 8)     // nt-subtile stride: 1168 B

typedef __attribute__((ext_vector_type(4))) float f32x4;
typedef __attribute__((ext_vector_type(4))) int   i32x4;
typedef __attribute__((ext_vector_type(8))) __bf16 bf16x8;

union PFrag { unsigned w[4]; bf16x8 f; };

static __device__ __forceinline__ unsigned bfbits(float x) {
    union { __bf16 b; unsigned short u; } cv; cv.b = (__bf16)x; return (unsigned)cv.u;
}
static __device__ __forceinline__ float lo16(unsigned u) { return __uint_as_float(u << 16); }
static __device__ __forceinline__ float hi16(unsigned u) { return __uint_as_float(u & 0xffff0000u); }
static __device__ __forceinline__ bf16x8 cvt8(f32x4 a, f32x4 b) {
    bf16x8 f;
    f[0]=(__bf16)a[0]; f[1]=(__bf16)a[1]; f[2]=(__bf16)a[2]; f[3]=(__bf16)a[3];
    f[4]=(__bf16)b[0]; f[5]=(__bf16)b[1]; f[6]=(__bf16)b[2]; f[7]=(__bf16)b[3];
    return f;
}
static __device__ __forceinline__ unsigned nib4(i32x4 mm) {
    return (mm[0]?1u:0u) | (mm[1]?2u:0u) | (mm[2]?4u:0u) | (mm[3]?8u:0u);
}

struct WaveBuf {
    union {
        __bf16 vbuf[4 * NTSTR];      // V chunk, [nt][k][c] padded
        float  ctx[QBLK * DIM];      // ctx partial (used after PV)
    };
};
struct SharedT {
    WaveBuf sw[NWAVE];
    float red_m[QBLK][NWAVE];
    float red_s[QBLK][NWAVE];
};

__global__ __launch_bounds__(THREADS, 4)
void sdpa_mfma16(const float* __restrict__ Q, const float* __restrict__ K,
                 const float* __restrict__ V, const int* __restrict__ mask,
                 float* __restrict__ ctx_out, float* __restrict__ prob_out) {
    __shared__ SharedT su;

    // XCD-aware swizzle: 8192 = 8 XCDs x 1024 contiguous q-blocks (8 bh per XCD).
    const int rb   = ((blockIdx.x & 7) << 10) + (blockIdx.x >> 3);
    const int bh   = rb >> 7;
    const int q0   = (rb & 127) * QBLK;
    const int t    = threadIdx.x;
    const int lane = t & 63;
    const int w    = t >> 6;
    const int g    = lane >> 4;          // 0..3
    const int c    = lane & 15;          // lane's q-row (and N-col)

    const size_t bh_off = (size_t)bh * SEQ * DIM;
    const float* Qb = Q + bh_off;
    const float* Kb = K + bh_off;
    const float* Vb = V + bh_off;
    const int*   Mb = mask + (size_t)bh * SEQ * SEQ;
    const int wbase = w * KPW;

    // ---- Q^T B-fragments ----
    bf16x8 qf[2];
    {
        const float* qr = Qb + (size_t)(q0 + c) * DIM + 8 * g;
        qf[0] = cvt8(*(const f32x4*)(qr),      *(const f32x4*)(qr + 4));
        qf[1] = cvt8(*(const f32x4*)(qr + 32), *(const f32x4*)(qr + 36));
    }

    // =============== QK^T in 2 half-passes with clean VMEM queues (r15) ===============
    unsigned sc_pk[2 * NCT];             // 64 scores, packed bf16, UNMASKED
    unsigned mbits0 = 0u, mbits1 = 0u;   // 64 mask bits (4 per tile)
    const int* mrow = Mb + (size_t)(q0 + c) * SEQ + wbase + 4 * g;
    f32x4 kr[4];
    i32x4 mq[8];

    // ---- half 1: mask tiles 0-7 issued FIRST, then K-only loop ----
    #pragma unroll
    for (int j = 0; j < 8; ++j) mq[j] = *(const i32x4*)(mrow + 16 * j);
    __builtin_amdgcn_sched_barrier(0);   // pin: mask batch issues before anything below
    {
        const float* k0 = Kb + (size_t)(wbase + c) * DIM + 8 * g;
        kr[0] = *(const f32x4*)(k0);      kr[1] = *(const f32x4*)(k0 + 4);
        kr[2] = *(const f32x4*)(k0 + 32); kr[3] = *(const f32x4*)(k0 + 36);
    }
    #pragma unroll
    for (int ct = 0; ct < 8; ++ct) {
        bf16x8 kf0 = cvt8(kr[0], kr[1]);   // first iter: one mask-batch drain; rest clean
        bf16x8 kf1 = cvt8(kr[2], kr[3]);
        {   // reload next tile's K (tile 8 at ct==7 feeds half 2 seamlessly)
            const float* kn = Kb + (size_t)(wbase + (ct + 1) * 16 + c) * DIM + 8 * g;
            kr[0] = *(const f32x4*)(kn);      kr[1] = *(const f32x4*)(kn + 4);
            kr[2] = *(const f32x4*)(kn + 32); kr[3] = *(const f32x4*)(kn + 36);
        }
        f32x4 acc = {0.f, 0.f, 0.f, 0.f};
        acc = __builtin_amdgcn_mfma_f32_16x16x32_bf16(kf0, qf[0], acc, 0, 0, 0);
        acc = __builtin_amdgcn_mfma_f32_16x16x32_bf16(kf1, qf[1], acc, 0, 0, 0);
        sc_pk[2 * ct]     = bfbits(acc[0] * SCALE) | (bfbits(acc[1] * SCALE) << 16);
        sc_pk[2 * ct + 1] = bfbits(acc[2] * SCALE) | (bfbits(acc[3] * SCALE) << 16);
    }
    #pragma unroll
    for (int j = 0; j < 8; ++j) mbits0 |= nib4(mq[j]) << (4 * j);   // loads long retired

    // ---- half 2: mask tiles 8-15 issued FIRST, then K-only loop ----
    #pragma unroll
    for (int j = 0; j < 8; ++j) mq[j] = *(const i32x4*)(mrow + 16 * (8 + j));
    __builtin_amdgcn_sched_barrier(0);
    #pragma unroll
    for (int ct = 8; ct < NCT; ++ct) {
        bf16x8 kf0 = cvt8(kr[0], kr[1]);   // ct=8's K was issued BEFORE the mask batch: clean
        bf16x8 kf1 = cvt8(kr[2], kr[3]);
        if (ct + 1 < NCT) {
            const float* kn = Kb + (size_t)(wbase + (ct + 1) * 16 + c) * DIM + 8 * g;
            kr[0] = *(const f32x4*)(kn);      kr[1] = *(const f32x4*)(kn + 4);
            kr[2] = *(const f32x4*)(kn + 32); kr[3] = *(const f32x4*)(kn + 36);
        }
        f32x4 acc = {0.f, 0.f, 0.f, 0.f};
        acc = __builtin_amdgcn_mfma_f32_16x16x32_bf16(kf0, qf[0], acc, 0, 0, 0);
        acc = __builtin_amdgcn_mfma_f32_16x16x32_bf16(kf1, qf[1], acc, 0, 0, 0);
        sc_pk[2 * ct]     = bfbits(acc[0] * SCALE) | (bfbits(acc[1] * SCALE) << 16);
        sc_pk[2 * ct + 1] = bfbits(acc[2] * SCALE) | (bfbits(acc[3] * SCALE) << 16);
    }
    #pragma unroll
    for (int j = 0; j < 8; ++j) mbits1 |= nib4(mq[j]) << (4 * j);

    // ---- V chunk-0 prefetch: in flight across sweep + the single barrier ----
    const int r_st = lane >> 4;
    const int cw   = (4 * c) & 15;
    const int ntw  = c >> 2;
    f32x4 vrawA[4], vrawB[4];
    {
        const float* vsrc = Vb + (size_t)(wbase + r_st) * DIM + 4 * c;
        #pragma unroll
        for (int i = 0; i < 4; ++i) {
            vrawA[i] = *(const f32x4*)(vsrc + (size_t)(4 * i) * DIM);
            vrawB[i] = *(const f32x4*)(vsrc + (size_t)(16 + 4 * i) * DIM);
        }
    }

    // apply mask to packed scores (branchless select)
    #pragma unroll
    for (int ct = 0; ct < NCT; ++ct) {
        unsigned nib = ((ct < 8) ? (mbits0 >> (4 * ct)) : (mbits1 >> (4 * (ct - 8)))) & 0xFu;
        float x0 = (nib & 1u) ? -1e9f : lo16(sc_pk[2 * ct]);
        float x1 = (nib & 2u) ? -1e9f : hi16(sc_pk[2 * ct]);
        float x2 = (nib & 4u) ? -1e9f : lo16(sc_pk[2 * ct + 1]);
        float x3 = (nib & 8u) ? -1e9f : hi16(sc_pk[2 * ct + 1]);
        sc_pk[2 * ct]     = bfbits(x0) | (bfbits(x1) << 16);
        sc_pk[2 * ct + 1] = bfbits(x2) | (bfbits(x3) << 16);
    }

    // =============== single-barrier softmax: wave-local (mx, s_w) ===============
    float mx = -3e38f;
    #pragma unroll
    for (int i = 0; i < 2 * NCT; ++i)
        mx = fmaxf(mx, fmaxf(lo16(sc_pk[i]), hi16(sc_pk[i])));
    mx = fmaxf(mx, __shfl_xor(mx, 16));
    mx = fmaxf(mx, __shfl_xor(mx, 32));

    float sw_ = 0.f;
    #pragma unroll
    for (int i = 0; i < 2 * NCT; ++i) {
        float e0 = exp2f((lo16(sc_pk[i]) - mx) * LOG2E);
        float e1 = exp2f((hi16(sc_pk[i]) - mx) * LOG2E);
        sw_ += e0 + e1;
        sc_pk[i] = bfbits(e0) | (bfbits(e1) << 16);   // e' (wave-relative), bf16-packed
    }
    sw_ += __shfl_xor(sw_, 16);
    sw_ += __shfl_xor(sw_, 32);
    if (g == 0) { su.red_m[c][w] = mx; su.red_s[c][w] = sw_; }
    __syncthreads();    // THE softmax barrier (single)

    float fac;
    {
        float M = su.red_m[c][0];
        #pragma unroll
        for (int i = 1; i < NWAVE; ++i) M = fmaxf(M, su.red_m[c][i]);
        float S = 0.f;
        #pragma unroll
        for (int i = 0; i < NWAVE; ++i)
            S += su.red_s[c][i] * exp2f((su.red_m[c][i] - M) * LOG2E);
        fac = exp2f((mx - M) * LOG2E) / S;
    }
    float facr[4];
    #pragma unroll
    for (int jr = 0; jr < 4; ++jr) facr[jr] = __shfl(fac, 4 * g + jr);

    // =============== PV + prob write; P-fragment via shfl (no plds) ===============
    f32x4 cacc[4];
    #pragma unroll
    for (int nt = 0; nt < 4; ++nt) cacc[nt] = (f32x4){0.f, 0.f, 0.f, 0.f};

    const int  sA  = ((g & 1) << 5) + c;   // pf source lanes (r4 mapping, exonerated)
    const int  sB  = sA + 16;
    const bool hiT = (g >> 1) != 0;

    float* prow = prob_out + ((size_t)bh * SEQ + (q0 + c)) * SEQ + wbase;
    __bf16* vbufW = su.sw[w].vbuf;

    #pragma unroll
    for (int cc = 0; cc < NCHUNK; ++cc) {
        // stage chunk loaded last iteration / prologue
        #pragma unroll
        for (int i = 0; i < 4; ++i) {
            ushort2 lo_, hi_;
            lo_.x = (unsigned short)bfbits(vrawA[i][0]);
            lo_.y = (unsigned short)bfbits(vrawA[i][1]);
            hi_.x = (unsigned short)bfbits(vrawA[i][2]);
            hi_.y = (unsigned short)bfbits(vrawA[i][3]);
            __bf16* p = &vbufW[ntw * NTSTR + (4 * i + r_st) * VPAD + cw];
            *(ushort2*)p = lo_;
            *(ushort2*)(p + 2) = hi_;
        }
        #pragma unroll
        for (int i = 0; i < 4; ++i) {
            ushort2 lo_, hi_;
            lo_.x = (unsigned short)bfbits(vrawB[i][0]);
            lo_.y = (unsigned short)bfbits(vrawB[i][1]);
            hi_.x = (unsigned short)bfbits(vrawB[i][2]);
            hi_.y = (unsigned short)bfbits(vrawB[i][3]);
            __bf16* p = &vbufW[ntw * NTSTR + (16 + 4 * i + r_st) * VPAD + cw];
            *(ushort2*)p = lo_;
            *(ushort2*)(p + 2) = hi_;
        }
        // issue NEXT chunk's loads (only loads in this phase's queue)
        if (cc + 1 < NCHUNK) {
            const float* vsrc = Vb + (size_t)(wbase + (cc + 1) * 32 + r_st) * DIM + 4 * c;
            #pragma unroll
            for (int i = 0; i < 4; ++i) {
                vrawA[i] = *(const f32x4*)(vsrc + (size_t)(4 * i) * DIM);
                vrawB[i] = *(const f32x4*)(vsrc + (size_t)(16 + 4 * i) * DIM);
            }
        }

        // prob writes: pn = e' * fac (normalized)
        unsigned w0 = sc_pk[4 * cc],     w1 = sc_pk[4 * cc + 1];
        unsigned w2 = sc_pk[4 * cc + 2], w3 = sc_pk[4 * cc + 3];
        {
            f32x4 pnA = { lo16(w0) * fac, hi16(w0) * fac, lo16(w1) * fac, hi16(w1) * fac };
            f32x4 pnB = { lo16(w2) * fac, hi16(w2) * fac, lo16(w3) * fac, hi16(w3) * fac };
            *(f32x4*)(prow + 32 * cc + 4 * g)      = pnA;
            *(f32x4*)(prow + 32 * cc + 16 + 4 * g) = pnB;
        }

        // P A-fragment via cross-lane shfl (8 bpermute + 4 selects)
        PFrag pf;
        {
            unsigned a0 = __shfl(w0, sA), b0 = __shfl(w2, sA);
            pf.w[0] = hiT ? b0 : a0;
            unsigned a1 = __shfl(w1, sA), b1 = __shfl(w3, sA);
            pf.w[1] = hiT ? b1 : a1;
            unsigned a2 = __shfl(w0, sB), b2 = __shfl(w2, sB);
            pf.w[2] = hiT ? b2 : a2;
            unsigned a3 = __shfl(w1, sB), b3 = __shfl(w3, sB);
            pf.w[3] = hiT ? b3 : a3;
        }

        // V B-frags: conflict-free scalar column reads
        bf16x8 vfr[4];
        #pragma unroll
        for (int nt = 0; nt < 4; ++nt) {
            bf16x8 f;
            #pragma unroll
            for (int j = 0; j < 8; ++j)
                f[j] = vbufW[nt * NTSTR + (8 * g + j) * VPAD + c];
            vfr[nt] = f;
        }

        __builtin_amdgcn_s_setprio(1);
        #pragma unroll
        for (int nt = 0; nt < 4; ++nt)
            cacc[nt] = __builtin_amdgcn_mfma_f32_16x16x32_bf16(pf.f, vfr[nt], cacc[nt], 0, 0, 0);
        __builtin_amdgcn_s_setprio(0);
    }

    // =============== ctx partials (scaled by per-row fac) + cross-wave reduce ===============
    #pragma unroll
    for (int nt = 0; nt < 4; ++nt)
        #pragma unroll
        for (int jr = 0; jr < 4; ++jr)
            su.sw[w].ctx[(4 * g + jr) * DIM + nt * 16 + c] = cacc[nt][jr] * facr[jr];
    __syncthreads();
    {
        int e = t * 2;
        float2 a = make_float2(0.f, 0.f);
        #pragma unroll
        for (int i = 0; i < NWAVE; ++i) {
            float2 v = *(const float2*)&su.sw[i].ctx[e];
            a.x += v.x; a.y += v.y;
        }
        *(float2*)(ctx_out + ((size_t)bh * SEQ + q0) * DIM + e) = a;
    }
}

extern "C" void kernel_launch(void* const* d_in, const int* in_sizes, int n_in,
                              void* d_out, int out_size, void* d_ws, size_t ws_size,
                              hipStream_t stream) {
    const float* Q = (const float*)d_in[0];
    const float* K = (const float*)d_in[1];
    const float* V = (const float*)d_in[2];
    const int* mask = (const int*)d_in[3];
    float* ctx  = (float*)d_out;
    float* prob = (float*)d_out + (size_t)4 * 16 * SEQ * DIM;

    dim3 grid(64 * (SEQ / QBLK));   // 8192, divisible by 8 XCDs
    dim3 block(THREADS);
    sdpa_mfma16<<<grid, block, 0, stream>>>(Q, K, V, mask, ctx, prob);
}

// Round 19
// 943.464 us; speedup vs baseline: 1.8423x; 1.0608x over previous
//
#include <hip/hip_runtime.h>
#include <stdint.h>

// B=4,H=16,S=2048,D=64 fp32 SDPA with materialized attn_prob.
// r19: block-cooperative mask->bits prelude (coalesced 128KB sweep, 32:1
// compress into 4KB LDS) -> QK^T runs on a PURE K/L2 VMEM queue with 2-deep
// prefetch; mask state leaves the register file. PV/softmax = r18.
#define SEQ 2048
#define DIM 64
#define QBLK 16
#define NWAVE 8
#define KPW 256
#define NCT 16
#define NCHUNK 8
#define THREADS 512
#define SCALE 0.125f
#define LOG2E 1.4426950408889634f
#define VPAD 18                 // vbuf row stride in bf16 (36 B)
#define NTSTR (32*VPAD + 8)     // nt-subtile stride: 1168 B

typedef __attribute__((ext_vector_type(4))) float f32x4;
typedef __attribute__((ext_vector_type(4))) int   i32x4;
typedef __attribute__((ext_vector_type(8))) __bf16 bf16x8;

union PFrag { unsigned w[4]; bf16x8 f; };

static __device__ __forceinline__ unsigned bfbits(float x) {
    union { __bf16 b; unsigned short u; } cv; cv.b = (__bf16)x; return (unsigned)cv.u;
}
static __device__ __forceinline__ float lo16(unsigned u) { return __uint_as_float(u << 16); }
static __device__ __forceinline__ float hi16(unsigned u) { return __uint_as_float(u & 0xffff0000u); }
static __device__ __forceinline__ bf16x8 cvt8(f32x4 a, f32x4 b) {
    bf16x8 f;
    f[0]=(__bf16)a[0]; f[1]=(__bf16)a[1]; f[2]=(__bf16)a[2]; f[3]=(__bf16)a[3];
    f[4]=(__bf16)b[0]; f[5]=(__bf16)b[1]; f[6]=(__bf16)b[2]; f[7]=(__bf16)b[3];
    return f;
}
static __device__ __forceinline__ unsigned nib4(i32x4 mm) {
    return (mm[0]?1u:0u) | (mm[1]?2u:0u) | (mm[2]?4u:0u) | (mm[3]?8u:0u);
}

struct WaveBuf {
    union {
        __bf16 vbuf[4 * NTSTR];      // V chunk, [nt][k][c] padded
        float  ctx[QBLK * DIM];      // ctx partial (used after PV)
    };
};
struct SharedT {
    WaveBuf sw[NWAVE];               // 37376 B
    unsigned mb[QBLK][65];           // 4160 B: mask bits, 2048 bits/row, padded stride
    float red_m[QBLK][NWAVE];        // 512 B
    float red_s[QBLK][NWAVE];        // 512 B
};

__global__ __launch_bounds__(THREADS, 4)
void sdpa_mfma17(const float* __restrict__ Q, const float* __restrict__ K,
                 const float* __restrict__ V, const int* __restrict__ mask,
                 float* __restrict__ ctx_out, float* __restrict__ prob_out) {
    __shared__ SharedT su;

    // XCD-aware swizzle: 8192 = 8 XCDs x 1024 contiguous q-blocks (8 bh per XCD).
    const int rb   = ((blockIdx.x & 7) << 10) + (blockIdx.x >> 3);
    const int bh   = rb >> 7;
    const int q0   = (rb & 127) * QBLK;
    const int t    = threadIdx.x;
    const int lane = t & 63;
    const int w    = t >> 6;
    const int g    = lane >> 4;          // 0..3
    const int c    = lane & 15;          // lane's q-row (and N-col)

    const size_t bh_off = (size_t)bh * SEQ * DIM;
    const float* Qb = Q + bh_off;
    const float* Kb = K + bh_off;
    const float* Vb = V + bh_off;
    const int*   Mb = mask + (size_t)bh * SEQ * SEQ;
    const int wbase = w * KPW;

    // ---- Q^T B-fragments + K tiles 0,1 at HEAD of the VMEM queue ----
    bf16x8 qf[2];
    {
        const float* qr = Qb + (size_t)(q0 + c) * DIM + 8 * g;
        qf[0] = cvt8(*(const f32x4*)(qr),      *(const f32x4*)(qr + 4));
        qf[1] = cvt8(*(const f32x4*)(qr + 32), *(const f32x4*)(qr + 36));
    }
    f32x4 krA[4], krB[4];
    {
        const float* k0 = Kb + (size_t)(wbase + c) * DIM + 8 * g;
        krA[0] = *(const f32x4*)(k0);      krA[1] = *(const f32x4*)(k0 + 4);
        krA[2] = *(const f32x4*)(k0 + 32); krA[3] = *(const f32x4*)(k0 + 36);
        const float* k1 = Kb + (size_t)(wbase + 16 + c) * DIM + 8 * g;
        krB[0] = *(const f32x4*)(k1);      krB[1] = *(const f32x4*)(k1 + 4);
        krB[2] = *(const f32x4*)(k1 + 32); krB[3] = *(const f32x4*)(k1 + 36);
    }
    __builtin_amdgcn_sched_barrier(0);

    // =============== cooperative mask->bits prelude ===============
    // 16 row-sweeps; thread t loads ints [4t..4t+3] of row r (8KB coalesced),
    // compresses to 4 bits, OR-combines across 8-lane groups, one write/group.
    {
        const int* mstage = Mb + (size_t)q0 * SEQ + 4 * t;
        i32x4 ms[4];
        #pragma unroll
        for (int r = 0; r < 4; ++r)
            ms[r] = *(const i32x4*)(mstage + (size_t)r * SEQ);
        #pragma unroll
        for (int r = 0; r < QBLK; ++r) {
            i32x4 cur = ms[r & 3];
            if (r + 4 < QBLK)
                ms[r & 3] = *(const i32x4*)(mstage + (size_t)(r + 4) * SEQ);
            unsigned v = nib4(cur) << (4 * (lane & 7));
            v |= __shfl_xor(v, 1);
            v |= __shfl_xor(v, 2);
            v |= __shfl_xor(v, 4);
            if ((lane & 7) == 0)
                su.mb[r][w * 8 + (lane >> 3)] = v;
        }
    }

    // =============== QK^T: pure K/L2 queue, 2-tile-ahead prefetch ===============
    unsigned sc_pk[2 * NCT];             // 64 scores, packed bf16, UNMASKED
    #pragma unroll
    for (int ct = 0; ct < NCT; ++ct) {
        bf16x8 kf0, kf1;
        if ((ct & 1) == 0) { kf0 = cvt8(krA[0], krA[1]); kf1 = cvt8(krA[2], krA[3]); }
        else               { kf0 = cvt8(krB[0], krB[1]); kf1 = cvt8(krB[2], krB[3]); }
        if (ct + 2 < NCT) {  // reload the freed buffer with tile ct+2
            const float* kn = Kb + (size_t)(wbase + (ct + 2) * 16 + c) * DIM + 8 * g;
            if ((ct & 1) == 0) {
                krA[0] = *(const f32x4*)(kn);      krA[1] = *(const f32x4*)(kn + 4);
                krA[2] = *(const f32x4*)(kn + 32); krA[3] = *(const f32x4*)(kn + 36);
            } else {
                krB[0] = *(const f32x4*)(kn);      krB[1] = *(const f32x4*)(kn + 4);
                krB[2] = *(const f32x4*)(kn + 32); krB[3] = *(const f32x4*)(kn + 36);
            }
        }
        f32x4 acc = {0.f, 0.f, 0.f, 0.f};
        acc = __builtin_amdgcn_mfma_f32_16x16x32_bf16(kf0, qf[0], acc, 0, 0, 0);
        acc = __builtin_amdgcn_mfma_f32_16x16x32_bf16(kf1, qf[1], acc, 0, 0, 0);
        sc_pk[2 * ct]     = bfbits(acc[0] * SCALE) | (bfbits(acc[1] * SCALE) << 16);
        sc_pk[2 * ct + 1] = bfbits(acc[2] * SCALE) | (bfbits(acc[3] * SCALE) << 16);
    }

    // ---- V chunk-0 prefetch: in flight across both barriers ----
    const int r_st = lane >> 4;
    const int cw   = (4 * c) & 15;
    const int ntw  = c >> 2;
    f32x4 vrawA[4], vrawB[4];
    {
        const float* vsrc = Vb + (size_t)(wbase + r_st) * DIM + 4 * c;
        #pragma unroll
        for (int i = 0; i < 4; ++i) {
            vrawA[i] = *(const f32x4*)(vsrc + (size_t)(4 * i) * DIM);
            vrawB[i] = *(const f32x4*)(vsrc + (size_t)(16 + 4 * i) * DIM);
        }
    }

    __syncthreads();   // barrier #1: mb bits visible

    // apply mask bits from LDS (conflict-free: bank = (c + w*8 + j) mod 32)
    #pragma unroll
    for (int j = 0; j < 8; ++j) {
        unsigned word = su.mb[c][w * 8 + j];
        unsigned nibE = (word >> (4 * g)) & 0xFu;        // tile ct = 2j
        unsigned nibO = (word >> (16 + 4 * g)) & 0xFu;   // tile ct = 2j+1
        float x0 = (nibE & 1u) ? -1e9f : lo16(sc_pk[4 * j]);
        float x1 = (nibE & 2u) ? -1e9f : hi16(sc_pk[4 * j]);
        float x2 = (nibE & 4u) ? -1e9f : lo16(sc_pk[4 * j + 1]);
        float x3 = (nibE & 8u) ? -1e9f : hi16(sc_pk[4 * j + 1]);
        sc_pk[4 * j]     = bfbits(x0) | (bfbits(x1) << 16);
        sc_pk[4 * j + 1] = bfbits(x2) | (bfbits(x3) << 16);
        x0 = (nibO & 1u) ? -1e9f : lo16(sc_pk[4 * j + 2]);
        x1 = (nibO & 2u) ? -1e9f : hi16(sc_pk[4 * j + 2]);
        x2 = (nibO & 4u) ? -1e9f : lo16(sc_pk[4 * j + 3]);
        x3 = (nibO & 8u) ? -1e9f : hi16(sc_pk[4 * j + 3]);
        sc_pk[4 * j + 2] = bfbits(x0) | (bfbits(x1) << 16);
        sc_pk[4 * j + 3] = bfbits(x2) | (bfbits(x3) << 16);
    }

    // =============== single-exchange softmax: wave-local (mx, s_w) ===============
    float mx = -3e38f;
    #pragma unroll
    for (int i = 0; i < 2 * NCT; ++i)
        mx = fmaxf(mx, fmaxf(lo16(sc_pk[i]), hi16(sc_pk[i])));
    mx = fmaxf(mx, __shfl_xor(mx, 16));
    mx = fmaxf(mx, __shfl_xor(mx, 32));

    float sw_ = 0.f;
    #pragma unroll
    for (int i = 0; i < 2 * NCT; ++i) {
        float e0 = exp2f((lo16(sc_pk[i]) - mx) * LOG2E);
        float e1 = exp2f((hi16(sc_pk[i]) - mx) * LOG2E);
        sw_ += e0 + e1;
        sc_pk[i] = bfbits(e0) | (bfbits(e1) << 16);   // e' (wave-relative), bf16-packed
    }
    sw_ += __shfl_xor(sw_, 16);
    sw_ += __shfl_xor(sw_, 32);
    if (g == 0) { su.red_m[c][w] = mx; su.red_s[c][w] = sw_; }
    __syncthreads();   // barrier #2: (m,s) exchange

    float fac;
    {
        float M = su.red_m[c][0];
        #pragma unroll
        for (int i = 1; i < NWAVE; ++i) M = fmaxf(M, su.red_m[c][i]);
        float S = 0.f;
        #pragma unroll
        for (int i = 0; i < NWAVE; ++i)
            S += su.red_s[c][i] * exp2f((su.red_m[c][i] - M) * LOG2E);
        fac = exp2f((mx - M) * LOG2E) / S;
    }
    float facr[4];
    #pragma unroll
    for (int jr = 0; jr < 4; ++jr) facr[jr] = __shfl(fac, 4 * g + jr);

    // =============== PV + prob write; P-fragment via shfl (r18) ===============
    f32x4 cacc[4];
    #pragma unroll
    for (int nt = 0; nt < 4; ++nt) cacc[nt] = (f32x4){0.f, 0.f, 0.f, 0.f};

    const int  sA  = ((g & 1) << 5) + c;   // pf source lanes
    const int  sB  = sA + 16;
    const bool hiT = (g >> 1) != 0;

    float* prow = prob_out + ((size_t)bh * SEQ + (q0 + c)) * SEQ + wbase;
    __bf16* vbufW = su.sw[w].vbuf;

    #pragma unroll
    for (int cc = 0; cc < NCHUNK; ++cc) {
        // stage chunk loaded last iteration / prologue
        #pragma unroll
        for (int i = 0; i < 4; ++i) {
            ushort2 lo_, hi_;
            lo_.x = (unsigned short)bfbits(vrawA[i][0]);
            lo_.y = (unsigned short)bfbits(vrawA[i][1]);
            hi_.x = (unsigned short)bfbits(vrawA[i][2]);
            hi_.y = (unsigned short)bfbits(vrawA[i][3]);
            __bf16* p = &vbufW[ntw * NTSTR + (4 * i + r_st) * VPAD + cw];
            *(ushort2*)p = lo_;
            *(ushort2*)(p + 2) = hi_;
        }
        #pragma unroll
        for (int i = 0; i < 4; ++i) {
            ushort2 lo_, hi_;
            lo_.x = (unsigned short)bfbits(vrawB[i][0]);
            lo_.y = (unsigned short)bfbits(vrawB[i][1]);
            hi_.x = (unsigned short)bfbits(vrawB[i][2]);
            hi_.y = (unsigned short)bfbits(vrawB[i][3]);
            __bf16* p = &vbufW[ntw * NTSTR + (16 + 4 * i + r_st) * VPAD + cw];
            *(ushort2*)p = lo_;
            *(ushort2*)(p + 2) = hi_;
        }
        // issue NEXT chunk's loads
        if (cc + 1 < NCHUNK) {
            const float* vsrc = Vb + (size_t)(wbase + (cc + 1) * 32 + r_st) * DIM + 4 * c;
            #pragma unroll
            for (int i = 0; i < 4; ++i) {
                vrawA[i] = *(const f32x4*)(vsrc + (size_t)(4 * i) * DIM);
                vrawB[i] = *(const f32x4*)(vsrc + (size_t)(16 + 4 * i) * DIM);
            }
        }

        // prob writes: pn = e' * fac (normalized)
        unsigned w0 = sc_pk[4 * cc],     w1 = sc_pk[4 * cc + 1];
        unsigned w2 = sc_pk[4 * cc + 2], w3 = sc_pk[4 * cc + 3];
        {
            f32x4 pnA = { lo16(w0) * fac, hi16(w0) * fac, lo16(w1) * fac, hi16(w1) * fac };
            f32x4 pnB = { lo16(w2) * fac, hi16(w2) * fac, lo16(w3) * fac, hi16(w3) * fac };
            *(f32x4*)(prow + 32 * cc + 4 * g)      = pnA;
            *(f32x4*)(prow + 32 * cc + 16 + 4 * g) = pnB;
        }

        // P A-fragment via cross-lane shfl
        PFrag pf;
        {
            unsigned a0 = __shfl(w0, sA), b0 = __shfl(w2, sA);
            pf.w[0] = hiT ? b0 : a0;
            unsigned a1 = __shfl(w1, sA), b1 = __shfl(w3, sA);
            pf.w[1] = hiT ? b1 : a1;
            unsigned a2 = __shfl(w0, sB), b2 = __shfl(w2, sB);
            pf.w[2] = hiT ? b2 : a2;
            unsigned a3 = __shfl(w1, sB), b3 = __shfl(w3, sB);
            pf.w[3] = hiT ? b3 : a3;
        }

        // V B-frags: conflict-free scalar column reads
        bf16x8 vfr[4];
        #pragma unroll
        for (int nt = 0; nt < 4; ++nt) {
            bf16x8 f;
            #pragma unroll
            for (int j = 0; j < 8; ++j)
                f[j] = vbufW[nt * NTSTR + (8 * g + j) * VPAD + c];
            vfr[nt] = f;
        }

        __builtin_amdgcn_s_setprio(1);
        #pragma unroll
        for (int nt = 0; nt < 4; ++nt)
            cacc[nt] = __builtin_amdgcn_mfma_f32_16x16x32_bf16(pf.f, vfr[nt], cacc[nt], 0, 0, 0);
        __builtin_amdgcn_s_setprio(0);
    }

    // =============== ctx partials (scaled by per-row fac) + cross-wave reduce ===============
    #pragma unroll
    for (int nt = 0; nt < 4; ++nt)
        #pragma unroll
        for (int jr = 0; jr < 4; ++jr)
            su.sw[w].ctx[(4 * g + jr) * DIM + nt * 16 + c] = cacc[nt][jr] * facr[jr];
    __syncthreads();
    {
        int e = t * 2;
        float2 a = make_float2(0.f, 0.f);
        #pragma unroll
        for (int i = 0; i < NWAVE; ++i) {
            float2 v = *(const float2*)&su.sw[i].ctx[e];
            a.x += v.x; a.y += v.y;
        }
        *(float2*)(ctx_out + ((size_t)bh * SEQ + q0) * DIM + e) = a;
    }
}

extern "C" void kernel_launch(void* const* d_in, const int* in_sizes, int n_in,
                              void* d_out, int out_size, void* d_ws, size_t ws_size,
                              hipStream_t stream) {
    const float* Q = (const float*)d_in[0];
    const float* K = (const float*)d_in[1];
    const float* V = (const float*)d_in[2];
    const int* mask = (const int*)d_in[3];
    float* ctx  = (float*)d_out;
    float* prob = (float*)d_out + (size_t)4 * 16 * SEQ * DIM;

    dim3 grid(64 * (SEQ / QBLK));   // 8192, divisible by 8 XCDs
    dim3 block(THREADS);
    sdpa_mfma17<<<grid, block, 0, stream>>>(Q, K, V, mask, ctx, prob);
}